// Round 11
// baseline (225.949 us; speedup 1.0000x reference)
//
#include <hip/hip_runtime.h>
#include <math.h>

#define LL 2048
#define DD 128
#define NS 16                          // 2 sources * 8 batches
#define SLAB (LL * DD)                 // 262144 elements per (src,n)
#define SCALE 0.08838834764831845f     // 1/sqrt(128)

typedef __attribute__((ext_vector_type(8))) short short8v;   // 8 bf16 (4 VGPR)
typedef __attribute__((ext_vector_type(4))) float float4v;   // MFMA C/D

__device__ __forceinline__ unsigned int f2bf(float f) {   // RNE, low 16 bits
    unsigned int u = __float_as_uint(f);
    u += 0x7fffu + ((u >> 16) & 1u);
    return u >> 16;
}

// strip decode: 256 blocks, 1/CU. XCD k owns slabs ns=k,k+8 (L2-resident).
__device__ __forceinline__ void strip_decode(int bx, int by, int& ib, int& ns) {
    const int lin = by * 16 + bx;
    const int xcd = lin & 7;
    const int w   = lin >> 3;          // 0..31
    ns = xcd + 8 * (w & 1);
    ib = w >> 1;
}

// async global->LDS, 16B per lane; LDS dest = wave-uniform base + lane*16
__device__ __forceinline__ void gl_lds16(const void* g, void* l) {
    __builtin_amdgcn_global_load_lds(
        (const __attribute__((address_space(1))) void*)g,
        (__attribute__((address_space(3))) void*)l, 16, 0, 0);
}

// Stage one 128x32 bf16 chunk into a 512x16B-slot panel (512-thread block:
// 1 DMA instr/wave). Slot s=row*4+c' holds row's chunk oc=c'^((row>>1)&3)
// (XOR involution; same perm on read). Conflict-free (verified R3-R9: 0).
__device__ __forceinline__ void stage512(
    const unsigned short* __restrict__ gT, unsigned short* lbuf, int tid)
{
    const int row = tid >> 2;
    const int oc  = (tid & 3) ^ ((row >> 1) & 3);
    const int sb  = tid & ~63;                    // wave-uniform base slot
    gl_lds16(gT + (size_t)row * DD + oc * 8, lbuf + (size_t)sb * 8);
}

// stage one half-jb (2 kc) of B hi+lo into a 4-panel half-buffer (16 KB)
#define STAGE_HALF(DST, GH, GL, KC) do {                       \
    stage512((GH) + (KC) * 32,       (DST)[0], tid);           \
    stage512((GL) + (KC) * 32,       (DST)[1], tid);           \
    stage512((GH) + ((KC) + 1) * 32, (DST)[2], tid);           \
    stage512((GL) + ((KC) + 1) * 32, (DST)[3], tid); } while (0)

#define ZEROACC(ACC) do {                                      \
    _Pragma("unroll") for (int rt = 0; rt < 4; ++rt)           \
    _Pragma("unroll") for (int ct = 0; ct < 2; ++ct)           \
    _Pragma("unroll") for (int r = 0; r < 4; ++r) (ACC)[rt][ct][r] = 0.f; } while (0)

// one K-chunk: 4 ds_read_b128 (B only; A-lo pinned in registers),
// 24 MFMA (hh, hl, lh). R9 lesson: VGPR_Count=112 proved the compiler was
// REMATERIALIZING A frags per use; A-lo LDS reads (4/wave/kc) put the LDS
// pipe at/above the MFMA budget. A-lo is now register-resident (forced).
#define KC2(ACC, CB, KI, AKC) do {                                           \
    const unsigned short* BhP = (CB)[2 * (KI)];                              \
    const unsigned short* BlP = (CB)[2 * (KI) + 1];                          \
    short8v bh[2], bl[2];                                                    \
    _Pragma("unroll")                                                        \
    for (int ct = 0; ct < 2; ++ct) {                                         \
        const int r = wc * 32 + ct * 16 + l16;                               \
        const int off = r * 32 + ((quad ^ ((r >> 1) & 3)) << 3);             \
        bh[ct] = *(const short8v*)&BhP[off];                                 \
        bl[ct] = *(const short8v*)&BlP[off];                                 \
    }                                                                        \
    __builtin_amdgcn_s_setprio(1);                                           \
    _Pragma("unroll")                                                        \
    for (int rt = 0; rt < 4; ++rt)                                           \
    _Pragma("unroll")                                                        \
    for (int ct = 0; ct < 2; ++ct) {                                         \
        (ACC)[rt][ct] = __builtin_amdgcn_mfma_f32_16x16x32_bf16(ah[AKC][rt], bh[ct], (ACC)[rt][ct], 0, 0, 0); \
        (ACC)[rt][ct] = __builtin_amdgcn_mfma_f32_16x16x32_bf16(ah[AKC][rt], bl[ct], (ACC)[rt][ct], 0, 0, 0); \
        (ACC)[rt][ct] = __builtin_amdgcn_mfma_f32_16x16x32_bf16(alr[AKC][rt], bh[ct], (ACC)[rt][ct], 0, 0, 0); \
    }                                                                        \
    __builtin_amdgcn_s_setprio(0); } while (0)

// sweep-1 deferred epilogue: row-sum exp accumulation (same order as R6-R9)
#define EPI1(ACC) do {                                         \
    _Pragma("unroll") for (int rt = 0; rt < 4; ++rt)           \
    _Pragma("unroll") for (int rg = 0; rg < 4; ++rg) {         \
        float e0 = __expf((ACC)[rt][0][rg] * SCALE);           \
        float e1 = __expf((ACC)[rt][1][rg] * SCALE);           \
        z[rt][rg] += e0 + e1; } } while (0)

// sweep-2 deferred epilogue: weighted col partials (diag excluded), per R6-R9
#define EPI2(ACC, JBV) do {                                    \
    float colp0 = 0.f, colp1 = 0.f;                            \
    const bool dgj = ((JBV) == ib);                            \
    _Pragma("unroll") for (int rt = 0; rt < 4; ++rt)           \
    _Pragma("unroll") for (int rg = 0; rg < 4; ++rg) {         \
        const int rl = wr * 64 + rt * 16 + quad * 4 + rg;      \
        float e0 = __expf((ACC)[rt][0][rg] * SCALE);           \
        float e1 = __expf((ACC)[rt][1][rg] * SCALE);           \
        bool s0 = dgj && (rl == wc * 32 + l16);                \
        bool s1 = dgj && (rl == wc * 32 + 16 + l16);           \
        colp0 += s0 ? 0.f : e0 * wrow[rt][rg];                 \
        colp1 += s1 ? 0.f : e1 * wrow[rt][rg]; }               \
    colp0 += __shfl_xor(colp0, 16); colp0 += __shfl_xor(colp0, 32); \
    colp1 += __shfl_xor(colp1, 16); colp1 += __shfl_xor(colp1, 32); \
    if (quad == 0) {                                           \
        scs[(JBV) * 128 + wc * 32 + l16][wr]      = colp0;     \
        scs[(JBV) * 128 + wc * 32 + 16 + l16][wr] = colp1; } } while (0)

// ---------------------------------------------------------------------------
// Kernel 1: P = x @ W^T + b (fp32), split to P_hi/P_lo bf16 in d_out.
// R9 version (1 block/CU, single barrier, XOR-swizzled 16B chunks).
// ---------------------------------------------------------------------------
__global__ __launch_bounds__(512) void proj_kernel(
    const float* __restrict__ xt, const float* __restrict__ xf,
    const float* __restrict__ W,  const float* __restrict__ bias,
    unsigned short* __restrict__ Ph, unsigned short* __restrict__ Pl)
{
    __shared__ float Wl[128 * 128];    // 64 KB, XOR-swizzled 16B chunks
    __shared__ float Xl[128 * 128];    // 64 KB
    const int ns = blockIdx.y;
    const int l0 = blockIdx.x * 128;
    const int src = ns >> 3, n = ns & 7;
    const float* x = (src ? xf : xt) + (size_t)n * LL * DD + (size_t)l0 * DD;
    const int tid = threadIdx.x;
    const int ty = tid >> 4, tx = tid & 15;   // ty 0..31, tx 0..15

#pragma unroll
    for (int it = 0; it < 8; ++it) {
        const int s   = it * 512 + tid;
        const int row = s >> 5, c = s & 31;
        const int oc  = c ^ (row & 7);
        const int sb  = it * 512 + (tid & ~63);       // wave-uniform base slot
        gl_lds16(W + (size_t)row * DD + oc * 4, Wl + (size_t)sb * 4);
        gl_lds16(x + (size_t)row * DD + oc * 4, Xl + (size_t)sb * 4);
    }

    float acc[4][8];
#pragma unroll
    for (int i = 0; i < 4; ++i)
#pragma unroll
        for (int j = 0; j < 8; ++j) acc[i][j] = bias[tx + 16 * j];

    __syncthreads();                   // single barrier (drains all DMA)

    const int rs = ty & 7, ds = tx & 7;
#pragma unroll 4
    for (int k4 = 0; k4 < 128; k4 += 4) {
        const int c = k4 >> 2;
        float4 xv[4], wv[8];
#pragma unroll
        for (int i = 0; i < 4; ++i)
            xv[i] = *(const float4*)&Xl[(ty + 32 * i) * 128 + ((c ^ rs) << 2)];
#pragma unroll
        for (int j = 0; j < 8; ++j)
            wv[j] = *(const float4*)&Wl[(tx + 16 * j) * 128 + ((c ^ ds) << 2)];
#pragma unroll
        for (int i = 0; i < 4; ++i)
#pragma unroll
            for (int j = 0; j < 8; ++j) {
                acc[i][j] = fmaf(xv[i].x, wv[j].x, acc[i][j]);
                acc[i][j] = fmaf(xv[i].y, wv[j].y, acc[i][j]);
                acc[i][j] = fmaf(xv[i].z, wv[j].z, acc[i][j]);
                acc[i][j] = fmaf(xv[i].w, wv[j].w, acc[i][j]);
            }
    }

#pragma unroll
    for (int i = 0; i < 4; ++i) {
        const size_t rowo = (size_t)ns * SLAB + (size_t)(l0 + ty + 32 * i) * DD;
#pragma unroll
        for (int j = 0; j < 8; ++j) {
            float p = acc[i][j];
            unsigned int hb = f2bf(p);
            float hf = __uint_as_float(hb << 16);
            unsigned int lb = f2bf(p - hf);
            Ph[rowo + tx + 16 * j] = (unsigned short)hb;
            Pl[rowo + tx + 16 * j] = (unsigned short)lb;
        }
    }
}

// ---------------------------------------------------------------------------
// Kernel 2 (fused strip): R10/R11 change — A-lo pinned in 64 VGPRs via
// empty-asm keep-alive (defeats load rematerialization, R9 post-mortem).
// Alpan LDS deleted: inner-loop LDS traffic halves to 4 b128/wave/kc.
// launch_bounds (512,1): LDS (84 KB) already caps at 1 block/CU, so the
// min-waves=2 VGPR cap (256) bought nothing and risked spill with the
// +64 pinned regs — (512,1) raises the cap to 512, zero spill risk,
// identical occupancy. Numerics bitwise-identical to R7-R9.
// ---------------------------------------------------------------------------
__global__ __launch_bounds__(512, 1) void score_kernel(
    const unsigned short* __restrict__ Ph, const unsigned short* __restrict__ Pl,
    float* __restrict__ Spart)
{
    __shared__ unsigned short pan[2][4][4096];   // 64 KB B double-buffer
    __shared__ float scs[2048][2];               // 16 KB col partials
    __shared__ float zl[128][4];                 // 2 KB Z cross-wave
    int ib, ns;  strip_decode(blockIdx.x, blockIdx.y, ib, ns);
    const int tid = threadIdx.x;
    const int lane = tid & 63, quad = lane >> 4, l16 = lane & 15, wave = tid >> 6;
    const int wr = wave >> 2, wc = wave & 3;

    const unsigned short* sAh = Ph + (size_t)ns * SLAB + (size_t)ib * 128 * DD;
    const unsigned short* sAl = Pl + (size_t)ns * SLAB + (size_t)ib * 128 * DD;
    const unsigned short* sBh = Ph + (size_t)ns * SLAB;
    const unsigned short* sBl = Pl + (size_t)ns * SLAB;

    // ---- prologue: A-lo -> pinned regs, A-hi regs (compiler-managed),
    //      first half of jb0 -> LDS ----
    short8v alr[4][4];
#pragma unroll
    for (int kc = 0; kc < 4; ++kc)
#pragma unroll
        for (int rt = 0; rt < 4; ++rt)
            alr[kc][rt] = *(const short8v*)
                &sAl[(size_t)(wr * 64 + rt * 16 + l16) * DD + kc * 32 + quad * 8];
    // keep-alive: force whole-kernel residency (non-rematerializable)
#pragma unroll
    for (int kc = 0; kc < 4; ++kc)
#pragma unroll
        for (int rt = 0; rt < 4; ++rt)
            asm volatile("" : "+v"(alr[kc][rt]));

    STAGE_HALF(pan[0], sBh, sBl, 0);
    short8v ah[4][4];
#pragma unroll
    for (int kc = 0; kc < 4; ++kc)
#pragma unroll
        for (int rt = 0; rt < 4; ++rt)
            ah[kc][rt] = *(const short8v*)
                &sAh[(size_t)(wr * 64 + rt * 16 + l16) * DD + kc * 32 + quad * 8];
    __syncthreads();

    float4v accA[4][2], accB[4][2];
    float z[4][4];
#pragma unroll
    for (int rt = 0; rt < 4; ++rt)
#pragma unroll
        for (int rg = 0; rg < 4; ++rg) z[rt][rg] = 0.f;

    // ================= sweep 1: Z row sums =================
#pragma unroll 1
    for (int jp = 0; jp < 8; ++jp) {
        const unsigned short* b0h = sBh + (size_t)(2 * jp) * 128 * DD;
        const unsigned short* b0l = sBl + (size_t)(2 * jp) * 128 * DD;
        const unsigned short* b1h = b0h + 128 * DD;
        const unsigned short* b1l = b0l + 128 * DD;
        const unsigned short* b2h = b1h + 128 * DD;
        const unsigned short* b2l = b1l + 128 * DD;

        ZEROACC(accA);                         // phase A0: jb even, kc0-1
        STAGE_HALF(pan[1], b0h, b0l, 2);
        KC2(accA, pan[0], 0, 0);
        KC2(accA, pan[0], 1, 1);
        if (jp) EPI1(accB);                    // epilogue of jb 2jp-1
        __syncthreads();

        STAGE_HALF(pan[0], b1h, b1l, 0);       // phase A1: jb even, kc2-3
        KC2(accA, pan[1], 0, 2);
        KC2(accA, pan[1], 1, 3);
        __syncthreads();

        ZEROACC(accB);                         // phase B0: jb odd, kc0-1
        STAGE_HALF(pan[1], b1h, b1l, 2);
        KC2(accB, pan[0], 0, 0);
        KC2(accB, pan[0], 1, 1);
        EPI1(accA);                            // epilogue of jb 2jp
        __syncthreads();

        if (jp < 7) STAGE_HALF(pan[0], b2h, b2l, 0);   // phase B1: kc2-3
        KC2(accB, pan[1], 0, 2);
        KC2(accB, pan[1], 1, 3);
        __syncthreads();
    }
    EPI1(accB);                                // jb 15

    // ---- Z reduce -> per-thread iZ row weights ----
#pragma unroll
    for (int rt = 0; rt < 4; ++rt)
#pragma unroll
        for (int rg = 0; rg < 4; ++rg) {
            float s = z[rt][rg];
            s += __shfl_xor(s, 1);
            s += __shfl_xor(s, 2);
            s += __shfl_xor(s, 4);
            s += __shfl_xor(s, 8);
            if (l16 == 0) zl[wr * 64 + rt * 16 + quad * 4 + rg][wc] = s;
        }
    STAGE_HALF(pan[0], sBh, sBl, 0);           // prefetch sweep-2 jb0
    __syncthreads();
    float wrow[4][4];
#pragma unroll
    for (int rt = 0; rt < 4; ++rt)
#pragma unroll
        for (int rg = 0; rg < 4; ++rg) {
            const int row = wr * 64 + rt * 16 + quad * 4 + rg;
            wrow[rt][rg] = 1.0f / (zl[row][0] + zl[row][1] + zl[row][2] + zl[row][3]);
        }

    // ================= sweep 2: weighted col partials =================
#pragma unroll 1
    for (int jp = 0; jp < 8; ++jp) {
        const unsigned short* b0h = sBh + (size_t)(2 * jp) * 128 * DD;
        const unsigned short* b0l = sBl + (size_t)(2 * jp) * 128 * DD;
        const unsigned short* b1h = b0h + 128 * DD;
        const unsigned short* b1l = b0l + 128 * DD;
        const unsigned short* b2h = b1h + 128 * DD;
        const unsigned short* b2l = b1l + 128 * DD;

        ZEROACC(accA);
        STAGE_HALF(pan[1], b0h, b0l, 2);
        KC2(accA, pan[0], 0, 0);
        KC2(accA, pan[0], 1, 1);
        if (jp) EPI2(accB, 2 * jp - 1);
        __syncthreads();

        STAGE_HALF(pan[0], b1h, b1l, 0);
        KC2(accA, pan[1], 0, 2);
        KC2(accA, pan[1], 1, 3);
        __syncthreads();

        ZEROACC(accB);
        STAGE_HALF(pan[1], b1h, b1l, 2);
        KC2(accB, pan[0], 0, 0);
        KC2(accB, pan[0], 1, 1);
        EPI2(accA, 2 * jp);
        __syncthreads();

        if (jp < 7) STAGE_HALF(pan[0], b2h, b2l, 0);
        KC2(accB, pan[1], 0, 2);
        KC2(accB, pan[1], 1, 3);
        __syncthreads();
    }
    EPI2(accB, 15);

    __syncthreads();
#pragma unroll
    for (int g = 0; g < 4; ++g) {
        const int m = tid + g * 512;
        Spart[((size_t)ns * LL + m) * 16 + ib] = scs[m][0] + scs[m][1];
    }
}

// ---------------------------------------------------------------------------
// Kernel 3: exact bottom-k mask via rank counting (parallel, R8 version).
// ---------------------------------------------------------------------------
__global__ __launch_bounds__(512) void mask_kernel(
    const float* __restrict__ Spart, unsigned char* __restrict__ maskbuf)
{
    __shared__ double s[LL];
    const int ns = blockIdx.x;
    const int q4 = blockIdx.y;             // 0..3: which 512-row slice we rank
    const int tid = threadIdx.x;
#pragma unroll
    for (int g = 0; g < 4; ++g) {
        int m = tid + g * 512;
        const float* sp = Spart + ((size_t)ns * LL + m) * 16;
        double a = 0.0;
#pragma unroll
        for (int t = 0; t < 16; ++t) a += (double)sp[t];
        s[m] = a;
    }
    __syncthreads();
    const int i = q4 * 512 + tid;
    const double si = s[i];
    const double2* sv = (const double2*)s;
    int cnt = 0;
#pragma unroll 4
    for (int j = 0; j < LL / 2; ++j) {
        double2 p = sv[j];
        cnt += (p.x < si) ? 1 : 0;
        cnt += (p.y < si) ? 1 : 0;
    }
    maskbuf[ns * LL + i] = (cnt < 1024) ? 1 : 0;
}

// ---------------------------------------------------------------------------
// Kernel 4: blend, all fp32.
// ---------------------------------------------------------------------------
__global__ __launch_bounds__(256) void blend_kernel(
    const float* __restrict__ xt, const float* __restrict__ xf,
    const unsigned char* __restrict__ maskbuf, float* __restrict__ out)
{
    const int idx4 = blockIdx.x * 256 + threadIdx.x;
    const size_t q = (size_t)idx4 * 4;
    const int row = (int)(q >> 7);
    const float4 a = *(const float4*)(xt + q);
    const float4 b = *(const float4*)(xf + q);
    const int mt = maskbuf[row] & 1;
    const int mf = maskbuf[16384 + row] & 1;
    const bool ct = mt && !mf;
    const bool cf = mf && !mt;
    float4 av;
    av.x = 0.5f * (a.x + b.x);  av.y = 0.5f * (a.y + b.y);
    av.z = 0.5f * (a.z + b.z);  av.w = 0.5f * (a.w + b.w);
    float4 o0 = ct ? av : a;
    float4 o1 = cf ? av : b;
    *(float4*)(out + q)                   = o0;
    *(float4*)(out + (size_t)2097152 + q) = o1;
}

// ---------------------------------------------------------------------------
extern "C" void kernel_launch(void* const* d_in, const int* in_sizes, int n_in,
                              void* d_out, int out_size, void* d_ws, size_t ws_size,
                              hipStream_t stream)
{
    const float* xt = (const float*)d_in[0];
    const float* xf = (const float*)d_in[1];
    const float* W  = (const float*)d_in[2];
    const float* b  = (const float*)d_in[3];
    float* out = (float*)d_out;

    // d_out (16.8 MB) holds P split: Ph bf16 [0,8.39MB), Pl bf16 [8.39,16.8MB).
    unsigned short* Ph = (unsigned short*)d_out;
    unsigned short* Pl = Ph + (size_t)NS * SLAB;

    float* Spart = (float*)d_ws;                       // 524288 f
    unsigned char* maskbuf = (unsigned char*)(Spart + (size_t)16 * LL * 16);
    // total ws ~2.2 MB

    proj_kernel<<<dim3(16, NS), 512, 0, stream>>>(xt, xf, W, b, Ph, Pl);
    score_kernel<<<dim3(16, 16), 512, 0, stream>>>(Ph, Pl, Spart);
    mask_kernel<<<dim3(NS, 4), 512, 0, stream>>>(Spart, maskbuf);
    blend_kernel<<<2048, 256, 0, stream>>>(xt, xf, maskbuf, out);
}

// Round 12
// 221.313 us; speedup vs baseline: 1.0209x; 1.0209x over previous
//
#include <hip/hip_runtime.h>
#include <math.h>

#define LL 2048
#define DD 128
#define NS 16                          // 2 sources * 8 batches
#define SLAB (LL * DD)                 // 262144 elements per (src,n)
#define SCALE 0.08838834764831845f     // 1/sqrt(128)

typedef __attribute__((ext_vector_type(8))) short short8v;   // 8 bf16 (4 VGPR)
typedef __attribute__((ext_vector_type(4))) float float4v;   // MFMA C/D

__device__ __forceinline__ unsigned int f2bf(float f) {   // RNE, low 16 bits
    unsigned int u = __float_as_uint(f);
    u += 0x7fffu + ((u >> 16) & 1u);
    return u >> 16;
}

// strip decode: 256 blocks, 1/CU. XCD k owns slabs ns=k,k+8 (L2-resident).
__device__ __forceinline__ void strip_decode(int bx, int by, int& ib, int& ns) {
    const int lin = by * 16 + bx;
    const int xcd = lin & 7;
    const int w   = lin >> 3;          // 0..31
    ns = xcd + 8 * (w & 1);
    ib = w >> 1;
}

// async global->LDS, 16B per lane; LDS dest = wave-uniform base + lane*16
__device__ __forceinline__ void gl_lds16(const void* g, void* l) {
    __builtin_amdgcn_global_load_lds(
        (const __attribute__((address_space(1))) void*)g,
        (__attribute__((address_space(3))) void*)l, 16, 0, 0);
}

// Stage one 128x32 bf16 chunk into a 512x16B-slot panel (512-thread block:
// 1 DMA instr/wave). Slot s=row*4+c' holds row's chunk oc=c'^((row>>1)&3)
// (XOR involution; same perm on read). Conflict-free (verified R3-R11: 0).
__device__ __forceinline__ void stage512(
    const unsigned short* __restrict__ gT, unsigned short* lbuf, int tid)
{
    const int row = tid >> 2;
    const int oc  = (tid & 3) ^ ((row >> 1) & 3);
    const int sb  = tid & ~63;                    // wave-uniform base slot
    gl_lds16(gT + (size_t)row * DD + oc * 8, lbuf + (size_t)sb * 8);
}

// stage one half-jb (2 kc) of B hi+lo into a 4-panel half-buffer (16 KB)
#define STAGE_HALF(DST, GH, GL, KC) do {                       \
    stage512((GH) + (KC) * 32,       (DST)[0], tid);           \
    stage512((GL) + (KC) * 32,       (DST)[1], tid);           \
    stage512((GH) + ((KC) + 1) * 32, (DST)[2], tid);           \
    stage512((GL) + ((KC) + 1) * 32, (DST)[3], tid); } while (0)

#define ZEROACC(ACC) do {                                      \
    _Pragma("unroll") for (int rt = 0; rt < 4; ++rt)           \
    _Pragma("unroll") for (int ct = 0; ct < 2; ++ct)           \
    _Pragma("unroll") for (int r = 0; r < 4; ++r) (ACC)[rt][ct][r] = 0.f; } while (0)

// one K-chunk: 4+4 ds_read_b128 (B from half-buffer CB, A-lo from Alpan),
// 24 MFMA. R11 lesson: asm-pinning A-lo in VGPRs spilled to scratch
// (WRITE_SIZE 2->11.7 MB, score 107->120) — A-lo stays in LDS (R9 best).
// R12 change: MFMA emitted in THREE PASSES (all hh, all hl, all lh) so
// adjacent instructions target different accumulators — breaks the
// hh->hl->lh same-acc dependency chains that inflated MFMA time ~3x
// (MfmaUtil 0.37*107us = 40us busy vs 12.4us throughput work).
// Per-accumulator order is still hh,hl,lh -> numerics BITWISE-IDENTICAL.
#define KC2(ACC, CB, KI, AKC) do {                                           \
    const unsigned short* BhP = (CB)[2 * (KI)];                              \
    const unsigned short* BlP = (CB)[2 * (KI) + 1];                          \
    short8v bh[2], bl[2], alv[4];                                            \
    _Pragma("unroll")                                                        \
    for (int ct = 0; ct < 2; ++ct) {                                         \
        const int r = wc * 32 + ct * 16 + l16;                               \
        const int off = r * 32 + ((quad ^ ((r >> 1) & 3)) << 3);             \
        bh[ct] = *(const short8v*)&BhP[off];                                 \
        bl[ct] = *(const short8v*)&BlP[off];                                 \
    }                                                                        \
    _Pragma("unroll")                                                        \
    for (int rt = 0; rt < 4; ++rt) {                                         \
        const int r = wr * 64 + rt * 16 + l16;                               \
        const int off = r * 32 + ((quad ^ ((r >> 1) & 3)) << 3);             \
        alv[rt] = *(const short8v*)&Alpan[AKC][off];                         \
    }                                                                        \
    __builtin_amdgcn_s_setprio(1);                                           \
    _Pragma("unroll")                                                        \
    for (int rt = 0; rt < 4; ++rt)                                           \
    _Pragma("unroll")                                                        \
    for (int ct = 0; ct < 2; ++ct)                                           \
        (ACC)[rt][ct] = __builtin_amdgcn_mfma_f32_16x16x32_bf16(ah[AKC][rt], bh[ct], (ACC)[rt][ct], 0, 0, 0); \
    _Pragma("unroll")                                                        \
    for (int rt = 0; rt < 4; ++rt)                                           \
    _Pragma("unroll")                                                        \
    for (int ct = 0; ct < 2; ++ct)                                           \
        (ACC)[rt][ct] = __builtin_amdgcn_mfma_f32_16x16x32_bf16(ah[AKC][rt], bl[ct], (ACC)[rt][ct], 0, 0, 0); \
    _Pragma("unroll")                                                        \
    for (int rt = 0; rt < 4; ++rt)                                           \
    _Pragma("unroll")                                                        \
    for (int ct = 0; ct < 2; ++ct)                                           \
        (ACC)[rt][ct] = __builtin_amdgcn_mfma_f32_16x16x32_bf16(alv[rt], bh[ct], (ACC)[rt][ct], 0, 0, 0); \
    __builtin_amdgcn_s_setprio(0); } while (0)

// sweep-1 deferred epilogue: row-sum exp accumulation (same order as R6-R11)
#define EPI1(ACC) do {                                         \
    _Pragma("unroll") for (int rt = 0; rt < 4; ++rt)           \
    _Pragma("unroll") for (int rg = 0; rg < 4; ++rg) {         \
        float e0 = __expf((ACC)[rt][0][rg] * SCALE);           \
        float e1 = __expf((ACC)[rt][1][rg] * SCALE);           \
        z[rt][rg] += e0 + e1; } } while (0)

// sweep-2 deferred epilogue: weighted col partials (diag excluded), per R6-R11
#define EPI2(ACC, JBV) do {                                    \
    float colp0 = 0.f, colp1 = 0.f;                            \
    const bool dgj = ((JBV) == ib);                            \
    _Pragma("unroll") for (int rt = 0; rt < 4; ++rt)           \
    _Pragma("unroll") for (int rg = 0; rg < 4; ++rg) {         \
        const int rl = wr * 64 + rt * 16 + quad * 4 + rg;      \
        float e0 = __expf((ACC)[rt][0][rg] * SCALE);           \
        float e1 = __expf((ACC)[rt][1][rg] * SCALE);           \
        bool s0 = dgj && (rl == wc * 32 + l16);                \
        bool s1 = dgj && (rl == wc * 32 + 16 + l16);           \
        colp0 += s0 ? 0.f : e0 * wrow[rt][rg];                 \
        colp1 += s1 ? 0.f : e1 * wrow[rt][rg]; }               \
    colp0 += __shfl_xor(colp0, 16); colp0 += __shfl_xor(colp0, 32); \
    colp1 += __shfl_xor(colp1, 16); colp1 += __shfl_xor(colp1, 32); \
    if (quad == 0) {                                           \
        scs[(JBV) * 128 + wc * 32 + l16][wr]      = colp0;     \
        scs[(JBV) * 128 + wc * 32 + 16 + l16][wr] = colp1; } } while (0)

// ---------------------------------------------------------------------------
// Kernel 1: P = x @ W^T + b (fp32), split to P_hi/P_lo bf16 in d_out.
// R9 version (1 block/CU, single barrier, XOR-swizzled 16B chunks).
// ---------------------------------------------------------------------------
__global__ __launch_bounds__(512) void proj_kernel(
    const float* __restrict__ xt, const float* __restrict__ xf,
    const float* __restrict__ W,  const float* __restrict__ bias,
    unsigned short* __restrict__ Ph, unsigned short* __restrict__ Pl)
{
    __shared__ float Wl[128 * 128];    // 64 KB, XOR-swizzled 16B chunks
    __shared__ float Xl[128 * 128];    // 64 KB
    const int ns = blockIdx.y;
    const int l0 = blockIdx.x * 128;
    const int src = ns >> 3, n = ns & 7;
    const float* x = (src ? xf : xt) + (size_t)n * LL * DD + (size_t)l0 * DD;
    const int tid = threadIdx.x;
    const int ty = tid >> 4, tx = tid & 15;   // ty 0..31, tx 0..15

#pragma unroll
    for (int it = 0; it < 8; ++it) {
        const int s   = it * 512 + tid;
        const int row = s >> 5, c = s & 31;
        const int oc  = c ^ (row & 7);
        const int sb  = it * 512 + (tid & ~63);       // wave-uniform base slot
        gl_lds16(W + (size_t)row * DD + oc * 4, Wl + (size_t)sb * 4);
        gl_lds16(x + (size_t)row * DD + oc * 4, Xl + (size_t)sb * 4);
    }

    float acc[4][8];
#pragma unroll
    for (int i = 0; i < 4; ++i)
#pragma unroll
        for (int j = 0; j < 8; ++j) acc[i][j] = bias[tx + 16 * j];

    __syncthreads();                   // single barrier (drains all DMA)

    const int rs = ty & 7, ds = tx & 7;
#pragma unroll 4
    for (int k4 = 0; k4 < 128; k4 += 4) {
        const int c = k4 >> 2;
        float4 xv[4], wv[8];
#pragma unroll
        for (int i = 0; i < 4; ++i)
            xv[i] = *(const float4*)&Xl[(ty + 32 * i) * 128 + ((c ^ rs) << 2)];
#pragma unroll
        for (int j = 0; j < 8; ++j)
            wv[j] = *(const float4*)&Wl[(tx + 16 * j) * 128 + ((c ^ ds) << 2)];
#pragma unroll
        for (int i = 0; i < 4; ++i)
#pragma unroll
            for (int j = 0; j < 8; ++j) {
                acc[i][j] = fmaf(xv[i].x, wv[j].x, acc[i][j]);
                acc[i][j] = fmaf(xv[i].y, wv[j].y, acc[i][j]);
                acc[i][j] = fmaf(xv[i].z, wv[j].z, acc[i][j]);
                acc[i][j] = fmaf(xv[i].w, wv[j].w, acc[i][j]);
            }
    }

#pragma unroll
    for (int i = 0; i < 4; ++i) {
        const size_t rowo = (size_t)ns * SLAB + (size_t)(l0 + ty + 32 * i) * DD;
#pragma unroll
        for (int j = 0; j < 8; ++j) {
            float p = acc[i][j];
            unsigned int hb = f2bf(p);
            float hf = __uint_as_float(hb << 16);
            unsigned int lb = f2bf(p - hf);
            Ph[rowo + tx + 16 * j] = (unsigned short)hb;
            Pl[rowo + tx + 16 * j] = (unsigned short)lb;
        }
    }
}

// ---------------------------------------------------------------------------
// Kernel 2 (fused strip): R9 structure (A-lo in Alpan LDS — R11's reg-pin
// spilled to scratch and regressed; reverted). R12: 3-pass MFMA order in
// KC2 (see macro comment). Numerics bitwise-identical to R7-R9.
// ---------------------------------------------------------------------------
__global__ __launch_bounds__(512, 2) void score_kernel(
    const unsigned short* __restrict__ Ph, const unsigned short* __restrict__ Pl,
    float* __restrict__ Spart)
{
    __shared__ unsigned short pan[2][4][4096];   // 64 KB B double-buffer
    __shared__ unsigned short Alpan[4][4096];    // 32 KB A-lo panels (static)
    __shared__ float scs[2048][2];               // 16 KB col partials
    __shared__ float zl[128][4];                 // 2 KB Z cross-wave
    int ib, ns;  strip_decode(blockIdx.x, blockIdx.y, ib, ns);
    const int tid = threadIdx.x;
    const int lane = tid & 63, quad = lane >> 4, l16 = lane & 15, wave = tid >> 6;
    const int wr = wave >> 2, wc = wave & 3;

    const unsigned short* sAh = Ph + (size_t)ns * SLAB + (size_t)ib * 128 * DD;
    const unsigned short* sAl = Pl + (size_t)ns * SLAB + (size_t)ib * 128 * DD;
    const unsigned short* sBh = Ph + (size_t)ns * SLAB;
    const unsigned short* sBl = Pl + (size_t)ns * SLAB;

    // ---- prologue: A-lo panels, A-hi regs, first half of jb0 ----
    stage512(sAl,      Alpan[0], tid);
    stage512(sAl + 32, Alpan[1], tid);
    stage512(sAl + 64, Alpan[2], tid);
    stage512(sAl + 96, Alpan[3], tid);
    STAGE_HALF(pan[0], sBh, sBl, 0);
    short8v ah[4][4];
#pragma unroll
    for (int kc = 0; kc < 4; ++kc)
#pragma unroll
        for (int rt = 0; rt < 4; ++rt)
            ah[kc][rt] = *(const short8v*)
                &sAh[(size_t)(wr * 64 + rt * 16 + l16) * DD + kc * 32 + quad * 8];
    __syncthreads();

    float4v accA[4][2], accB[4][2];
    float z[4][4];
#pragma unroll
    for (int rt = 0; rt < 4; ++rt)
#pragma unroll
        for (int rg = 0; rg < 4; ++rg) z[rt][rg] = 0.f;

    // ================= sweep 1: Z row sums =================
#pragma unroll 1
    for (int jp = 0; jp < 8; ++jp) {
        const unsigned short* b0h = sBh + (size_t)(2 * jp) * 128 * DD;
        const unsigned short* b0l = sBl + (size_t)(2 * jp) * 128 * DD;
        const unsigned short* b1h = b0h + 128 * DD;
        const unsigned short* b1l = b0l + 128 * DD;
        const unsigned short* b2h = b1h + 128 * DD;
        const unsigned short* b2l = b1l + 128 * DD;

        ZEROACC(accA);                         // phase A0: jb even, kc0-1
        STAGE_HALF(pan[1], b0h, b0l, 2);
        KC2(accA, pan[0], 0, 0);
        KC2(accA, pan[0], 1, 1);
        if (jp) EPI1(accB);                    // epilogue of jb 2jp-1
        __syncthreads();

        STAGE_HALF(pan[0], b1h, b1l, 0);       // phase A1: jb even, kc2-3
        KC2(accA, pan[1], 0, 2);
        KC2(accA, pan[1], 1, 3);
        __syncthreads();

        ZEROACC(accB);                         // phase B0: jb odd, kc0-1
        STAGE_HALF(pan[1], b1h, b1l, 2);
        KC2(accB, pan[0], 0, 0);
        KC2(accB, pan[0], 1, 1);
        EPI1(accA);                            // epilogue of jb 2jp
        __syncthreads();

        if (jp < 7) STAGE_HALF(pan[0], b2h, b2l, 0);   // phase B1: kc2-3
        KC2(accB, pan[1], 0, 2);
        KC2(accB, pan[1], 1, 3);
        __syncthreads();
    }
    EPI1(accB);                                // jb 15

    // ---- Z reduce -> per-thread iZ row weights ----
#pragma unroll
    for (int rt = 0; rt < 4; ++rt)
#pragma unroll
        for (int rg = 0; rg < 4; ++rg) {
            float s = z[rt][rg];
            s += __shfl_xor(s, 1);
            s += __shfl_xor(s, 2);
            s += __shfl_xor(s, 4);
            s += __shfl_xor(s, 8);
            if (l16 == 0) zl[wr * 64 + rt * 16 + quad * 4 + rg][wc] = s;
        }
    STAGE_HALF(pan[0], sBh, sBl, 0);           // prefetch sweep-2 jb0
    __syncthreads();
    float wrow[4][4];
#pragma unroll
    for (int rt = 0; rt < 4; ++rt)
#pragma unroll
        for (int rg = 0; rg < 4; ++rg) {
            const int row = wr * 64 + rt * 16 + quad * 4 + rg;
            wrow[rt][rg] = 1.0f / (zl[row][0] + zl[row][1] + zl[row][2] + zl[row][3]);
        }

    // ================= sweep 2: weighted col partials =================
#pragma unroll 1
    for (int jp = 0; jp < 8; ++jp) {
        const unsigned short* b0h = sBh + (size_t)(2 * jp) * 128 * DD;
        const unsigned short* b0l = sBl + (size_t)(2 * jp) * 128 * DD;
        const unsigned short* b1h = b0h + 128 * DD;
        const unsigned short* b1l = b0l + 128 * DD;
        const unsigned short* b2h = b1h + 128 * DD;
        const unsigned short* b2l = b1l + 128 * DD;

        ZEROACC(accA);
        STAGE_HALF(pan[1], b0h, b0l, 2);
        KC2(accA, pan[0], 0, 0);
        KC2(accA, pan[0], 1, 1);
        if (jp) EPI2(accB, 2 * jp - 1);
        __syncthreads();

        STAGE_HALF(pan[0], b1h, b1l, 0);
        KC2(accA, pan[1], 0, 2);
        KC2(accA, pan[1], 1, 3);
        __syncthreads();

        ZEROACC(accB);
        STAGE_HALF(pan[1], b1h, b1l, 2);
        KC2(accB, pan[0], 0, 0);
        KC2(accB, pan[0], 1, 1);
        EPI2(accA, 2 * jp);
        __syncthreads();

        if (jp < 7) STAGE_HALF(pan[0], b2h, b2l, 0);
        KC2(accB, pan[1], 0, 2);
        KC2(accB, pan[1], 1, 3);
        __syncthreads();
    }
    EPI2(accB, 15);

    __syncthreads();
#pragma unroll
    for (int g = 0; g < 4; ++g) {
        const int m = tid + g * 512;
        Spart[((size_t)ns * LL + m) * 16 + ib] = scs[m][0] + scs[m][1];
    }
}

// ---------------------------------------------------------------------------
// Kernel 3: exact bottom-k mask via rank counting (parallel, R8 version).
// ---------------------------------------------------------------------------
__global__ __launch_bounds__(512) void mask_kernel(
    const float* __restrict__ Spart, unsigned char* __restrict__ maskbuf)
{
    __shared__ double s[LL];
    const int ns = blockIdx.x;
    const int q4 = blockIdx.y;             // 0..3: which 512-row slice we rank
    const int tid = threadIdx.x;
#pragma unroll
    for (int g = 0; g < 4; ++g) {
        int m = tid + g * 512;
        const float* sp = Spart + ((size_t)ns * LL + m) * 16;
        double a = 0.0;
#pragma unroll
        for (int t = 0; t < 16; ++t) a += (double)sp[t];
        s[m] = a;
    }
    __syncthreads();
    const int i = q4 * 512 + tid;
    const double si = s[i];
    const double2* sv = (const double2*)s;
    int cnt = 0;
#pragma unroll 4
    for (int j = 0; j < LL / 2; ++j) {
        double2 p = sv[j];
        cnt += (p.x < si) ? 1 : 0;
        cnt += (p.y < si) ? 1 : 0;
    }
    maskbuf[ns * LL + i] = (cnt < 1024) ? 1 : 0;
}

// ---------------------------------------------------------------------------
// Kernel 4: blend, all fp32.
// ---------------------------------------------------------------------------
__global__ __launch_bounds__(256) void blend_kernel(
    const float* __restrict__ xt, const float* __restrict__ xf,
    const unsigned char* __restrict__ maskbuf, float* __restrict__ out)
{
    const int idx4 = blockIdx.x * 256 + threadIdx.x;
    const size_t q = (size_t)idx4 * 4;
    const int row = (int)(q >> 7);
    const float4 a = *(const float4*)(xt + q);
    const float4 b = *(const float4*)(xf + q);
    const int mt = maskbuf[row] & 1;
    const int mf = maskbuf[16384 + row] & 1;
    const bool ct = mt && !mf;
    const bool cf = mf && !mt;
    float4 av;
    av.x = 0.5f * (a.x + b.x);  av.y = 0.5f * (a.y + b.y);
    av.z = 0.5f * (a.z + b.z);  av.w = 0.5f * (a.w + b.w);
    float4 o0 = ct ? av : a;
    float4 o1 = cf ? av : b;
    *(float4*)(out + q)                   = o0;
    *(float4*)(out + (size_t)2097152 + q) = o1;
}

// ---------------------------------------------------------------------------
extern "C" void kernel_launch(void* const* d_in, const int* in_sizes, int n_in,
                              void* d_out, int out_size, void* d_ws, size_t ws_size,
                              hipStream_t stream)
{
    const float* xt = (const float*)d_in[0];
    const float* xf = (const float*)d_in[1];
    const float* W  = (const float*)d_in[2];
    const float* b  = (const float*)d_in[3];
    float* out = (float*)d_out;

    // d_out (16.8 MB) holds P split: Ph bf16 [0,8.39MB), Pl bf16 [8.39,16.8MB).
    unsigned short* Ph = (unsigned short*)d_out;
    unsigned short* Pl = Ph + (size_t)NS * SLAB;

    float* Spart = (float*)d_ws;                       // 524288 f
    unsigned char* maskbuf = (unsigned char*)(Spart + (size_t)16 * LL * 16);
    // total ws ~2.2 MB

    proj_kernel<<<dim3(16, NS), 512, 0, stream>>>(xt, xf, W, b, Ph, Pl);
    score_kernel<<<dim3(16, 16), 512, 0, stream>>>(Ph, Pl, Spart);
    mask_kernel<<<dim3(NS, 4), 512, 0, stream>>>(Spart, maskbuf);
    blend_kernel<<<2048, 256, 0, stream>>>(xt, xf, maskbuf, out);
}

// Round 13
// 197.144 us; speedup vs baseline: 1.1461x; 1.1226x over previous
//
#include <hip/hip_runtime.h>
#include <math.h>

#define LL 2048
#define DD 128
#define NS 16                          // 2 sources * 8 batches
#define SLAB (LL * DD)                 // 262144 elements per (src,n)
#define SCALE 0.08838834764831845f     // 1/sqrt(128)

typedef __attribute__((ext_vector_type(8))) short short8v;   // 8 bf16 (4 VGPR)
typedef __attribute__((ext_vector_type(4))) float float4v;   // MFMA C/D

__device__ __forceinline__ unsigned int f2bf(float f) {   // RNE, low 16 bits
    unsigned int u = __float_as_uint(f);
    u += 0x7fffu + ((u >> 16) & 1u);
    return u >> 16;
}

// strip decode: 256 blocks, 1/CU. XCD k owns slabs ns=k,k+8 (L2-resident).
__device__ __forceinline__ void strip_decode(int bx, int by, int& ib, int& ns) {
    const int lin = by * 16 + bx;
    const int xcd = lin & 7;
    const int w   = lin >> 3;          // 0..31
    ns = xcd + 8 * (w & 1);
    ib = w >> 1;
}

// async global->LDS, 16B per lane; LDS dest = wave-uniform base + lane*16
__device__ __forceinline__ void gl_lds16(const void* g, void* l) {
    __builtin_amdgcn_global_load_lds(
        (const __attribute__((address_space(1))) void*)g,
        (__attribute__((address_space(3))) void*)l, 16, 0, 0);
}

// Stage one 128x32 bf16 chunk into a 512x16B-slot panel (512-thread block:
// 1 DMA instr/wave). Slot s=row*4+c' holds row's chunk oc=c'^((row>>1)&3)
// (XOR involution; same perm on read). Conflict-free (verified R3-R12: 0).
__device__ __forceinline__ void stage512(
    const unsigned short* __restrict__ gT, unsigned short* lbuf, int tid)
{
    const int row = tid >> 2;
    const int oc  = (tid & 3) ^ ((row >> 1) & 3);
    const int sb  = tid & ~63;                    // wave-uniform base slot
    gl_lds16(gT + (size_t)row * DD + oc * 8, lbuf + (size_t)sb * 8);
}

// stage one half-jb (2 kc) of B hi+lo into a 4-panel half-buffer (16 KB)
#define STAGE_HALF(DST, GH, GL, KC) do {                       \
    stage512((GH) + (KC) * 32,       (DST)[0], tid);           \
    stage512((GL) + (KC) * 32,       (DST)[1], tid);           \
    stage512((GH) + ((KC) + 1) * 32, (DST)[2], tid);           \
    stage512((GL) + ((KC) + 1) * 32, (DST)[3], tid); } while (0)

#define ZEROACC(ACC) do {                                      \
    _Pragma("unroll") for (int rt = 0; rt < 4; ++rt)           \
    _Pragma("unroll") for (int ct = 0; ct < 2; ++ct)           \
    _Pragma("unroll") for (int r = 0; r < 4; ++r) (ACC)[rt][ct][r] = 0.f; } while (0)

// one K-chunk: 4+4 ds_read_b128 (B from half-buffer CB, A-lo from Alpan),
// 24 MFMA (hh, hl, lh). R12 result: MFMA emission order is a compiler
// no-op (null) — keep simple order.
#define KC2(ACC, CB, KI, AKC) do {                                           \
    const unsigned short* BhP = (CB)[2 * (KI)];                              \
    const unsigned short* BlP = (CB)[2 * (KI) + 1];                          \
    short8v bh[2], bl[2], alv[4];                                            \
    _Pragma("unroll")                                                        \
    for (int ct = 0; ct < 2; ++ct) {                                         \
        const int r = wc * 32 + ct * 16 + l16;                               \
        const int off = r * 32 + ((quad ^ ((r >> 1) & 3)) << 3);             \
        bh[ct] = *(const short8v*)&BhP[off];                                 \
        bl[ct] = *(const short8v*)&BlP[off];                                 \
    }                                                                        \
    _Pragma("unroll")                                                        \
    for (int rt = 0; rt < 4; ++rt) {                                         \
        const int r = wr * 64 + rt * 16 + l16;                               \
        const int off = r * 32 + ((quad ^ ((r >> 1) & 3)) << 3);             \
        alv[rt] = *(const short8v*)&Alpan[AKC][off];                         \
    }                                                                        \
    __builtin_amdgcn_s_setprio(1);                                           \
    _Pragma("unroll")                                                        \
    for (int rt = 0; rt < 4; ++rt)                                           \
    _Pragma("unroll")                                                        \
    for (int ct = 0; ct < 2; ++ct) {                                         \
        (ACC)[rt][ct] = __builtin_amdgcn_mfma_f32_16x16x32_bf16(ah[AKC][rt], bh[ct], (ACC)[rt][ct], 0, 0, 0); \
        (ACC)[rt][ct] = __builtin_amdgcn_mfma_f32_16x16x32_bf16(ah[AKC][rt], bl[ct], (ACC)[rt][ct], 0, 0, 0); \
        (ACC)[rt][ct] = __builtin_amdgcn_mfma_f32_16x16x32_bf16(alv[rt],     bh[ct], (ACC)[rt][ct], 0, 0, 0); \
    }                                                                        \
    __builtin_amdgcn_s_setprio(0); } while (0)

// sweep-1 deferred epilogue: row-sum exp accumulation (same order as R6-R12)
#define EPI1(ACC) do {                                         \
    _Pragma("unroll") for (int rt = 0; rt < 4; ++rt)           \
    _Pragma("unroll") for (int rg = 0; rg < 4; ++rg) {         \
        float e0 = __expf((ACC)[rt][0][rg] * SCALE);           \
        float e1 = __expf((ACC)[rt][1][rg] * SCALE);           \
        z[rt][rg] += e0 + e1; } } while (0)

// sweep-2 deferred epilogue: weighted col partials (diag excluded), per R6-R12
#define EPI2(ACC, JBV) do {                                    \
    float colp0 = 0.f, colp1 = 0.f;                            \
    const bool dgj = ((JBV) == ib);                            \
    _Pragma("unroll") for (int rt = 0; rt < 4; ++rt)           \
    _Pragma("unroll") for (int rg = 0; rg < 4; ++rg) {         \
        const int rl = wr * 64 + rt * 16 + quad * 4 + rg;      \
        float e0 = __expf((ACC)[rt][0][rg] * SCALE);           \
        float e1 = __expf((ACC)[rt][1][rg] * SCALE);           \
        bool s0 = dgj && (rl == wc * 32 + l16);                \
        bool s1 = dgj && (rl == wc * 32 + 16 + l16);           \
        colp0 += s0 ? 0.f : e0 * wrow[rt][rg];                 \
        colp1 += s1 ? 0.f : e1 * wrow[rt][rg]; }               \
    colp0 += __shfl_xor(colp0, 16); colp0 += __shfl_xor(colp0, 32); \
    colp1 += __shfl_xor(colp1, 16); colp1 += __shfl_xor(colp1, 32); \
    if (quad == 0) {                                           \
        scs[(JBV) * 128 + wc * 32 + l16][wr]      = colp0;     \
        scs[(JBV) * 128 + wc * 32 + 16 + l16][wr] = colp1; } } while (0)

// ---------------------------------------------------------------------------
// Kernel 1: P = x @ W^T + b (fp32), split to P_hi/P_lo bf16 in d_out.
// R9 version (1 block/CU, single barrier, XOR-swizzled 16B chunks).
// ---------------------------------------------------------------------------
__global__ __launch_bounds__(512) void proj_kernel(
    const float* __restrict__ xt, const float* __restrict__ xf,
    const float* __restrict__ W,  const float* __restrict__ bias,
    unsigned short* __restrict__ Ph, unsigned short* __restrict__ Pl)
{
    __shared__ float Wl[128 * 128];    // 64 KB, XOR-swizzled 16B chunks
    __shared__ float Xl[128 * 128];    // 64 KB
    const int ns = blockIdx.y;
    const int l0 = blockIdx.x * 128;
    const int src = ns >> 3, n = ns & 7;
    const float* x = (src ? xf : xt) + (size_t)n * LL * DD + (size_t)l0 * DD;
    const int tid = threadIdx.x;
    const int ty = tid >> 4, tx = tid & 15;   // ty 0..31, tx 0..15

#pragma unroll
    for (int it = 0; it < 8; ++it) {
        const int s   = it * 512 + tid;
        const int row = s >> 5, c = s & 31;
        const int oc  = c ^ (row & 7);
        const int sb  = it * 512 + (tid & ~63);       // wave-uniform base slot
        gl_lds16(W + (size_t)row * DD + oc * 4, Wl + (size_t)sb * 4);
        gl_lds16(x + (size_t)row * DD + oc * 4, Xl + (size_t)sb * 4);
    }

    float acc[4][8];
#pragma unroll
    for (int i = 0; i < 4; ++i)
#pragma unroll
        for (int j = 0; j < 8; ++j) acc[i][j] = bias[tx + 16 * j];

    __syncthreads();                   // single barrier (drains all DMA)

    const int rs = ty & 7, ds = tx & 7;
#pragma unroll 4
    for (int k4 = 0; k4 < 128; k4 += 4) {
        const int c = k4 >> 2;
        float4 xv[4], wv[8];
#pragma unroll
        for (int i = 0; i < 4; ++i)
            xv[i] = *(const float4*)&Xl[(ty + 32 * i) * 128 + ((c ^ rs) << 2)];
#pragma unroll
        for (int j = 0; j < 8; ++j)
            wv[j] = *(const float4*)&Wl[(tx + 16 * j) * 128 + ((c ^ ds) << 2)];
#pragma unroll
        for (int i = 0; i < 4; ++i)
#pragma unroll
            for (int j = 0; j < 8; ++j) {
                acc[i][j] = fmaf(xv[i].x, wv[j].x, acc[i][j]);
                acc[i][j] = fmaf(xv[i].y, wv[j].y, acc[i][j]);
                acc[i][j] = fmaf(xv[i].z, wv[j].z, acc[i][j]);
                acc[i][j] = fmaf(xv[i].w, wv[j].w, acc[i][j]);
            }
    }

#pragma unroll
    for (int i = 0; i < 4; ++i) {
        const size_t rowo = (size_t)ns * SLAB + (size_t)(l0 + ty + 32 * i) * DD;
#pragma unroll
        for (int j = 0; j < 8; ++j) {
            float p = acc[i][j];
            unsigned int hb = f2bf(p);
            float hf = __uint_as_float(hb << 16);
            unsigned int lb = f2bf(p - hf);
            Ph[rowo + tx + 16 * j] = (unsigned short)hb;
            Pl[rowo + tx + 16 * j] = (unsigned short)lb;
        }
    }
}

// ---------------------------------------------------------------------------
// Kernel 2 (fused strip): unchanged from R12 (best: 106.4 us, MfmaUtil 41%).
// ---------------------------------------------------------------------------
__global__ __launch_bounds__(512, 2) void score_kernel(
    const unsigned short* __restrict__ Ph, const unsigned short* __restrict__ Pl,
    float* __restrict__ Spart)
{
    __shared__ unsigned short pan[2][4][4096];   // 64 KB B double-buffer
    __shared__ unsigned short Alpan[4][4096];    // 32 KB A-lo panels (static)
    __shared__ float scs[2048][2];               // 16 KB col partials
    __shared__ float zl[128][4];                 // 2 KB Z cross-wave
    int ib, ns;  strip_decode(blockIdx.x, blockIdx.y, ib, ns);
    const int tid = threadIdx.x;
    const int lane = tid & 63, quad = lane >> 4, l16 = lane & 15, wave = tid >> 6;
    const int wr = wave >> 2, wc = wave & 3;

    const unsigned short* sAh = Ph + (size_t)ns * SLAB + (size_t)ib * 128 * DD;
    const unsigned short* sAl = Pl + (size_t)ns * SLAB + (size_t)ib * 128 * DD;
    const unsigned short* sBh = Ph + (size_t)ns * SLAB;
    const unsigned short* sBl = Pl + (size_t)ns * SLAB;

    // ---- prologue: A-lo panels, A-hi regs, first half of jb0 ----
    stage512(sAl,      Alpan[0], tid);
    stage512(sAl + 32, Alpan[1], tid);
    stage512(sAl + 64, Alpan[2], tid);
    stage512(sAl + 96, Alpan[3], tid);
    STAGE_HALF(pan[0], sBh, sBl, 0);
    short8v ah[4][4];
#pragma unroll
    for (int kc = 0; kc < 4; ++kc)
#pragma unroll
        for (int rt = 0; rt < 4; ++rt)
            ah[kc][rt] = *(const short8v*)
                &sAh[(size_t)(wr * 64 + rt * 16 + l16) * DD + kc * 32 + quad * 8];
    __syncthreads();

    float4v accA[4][2], accB[4][2];
    float z[4][4];
#pragma unroll
    for (int rt = 0; rt < 4; ++rt)
#pragma unroll
        for (int rg = 0; rg < 4; ++rg) z[rt][rg] = 0.f;

    // ================= sweep 1: Z row sums =================
#pragma unroll 1
    for (int jp = 0; jp < 8; ++jp) {
        const unsigned short* b0h = sBh + (size_t)(2 * jp) * 128 * DD;
        const unsigned short* b0l = sBl + (size_t)(2 * jp) * 128 * DD;
        const unsigned short* b1h = b0h + 128 * DD;
        const unsigned short* b1l = b0l + 128 * DD;
        const unsigned short* b2h = b1h + 128 * DD;
        const unsigned short* b2l = b1l + 128 * DD;

        ZEROACC(accA);                         // phase A0: jb even, kc0-1
        STAGE_HALF(pan[1], b0h, b0l, 2);
        KC2(accA, pan[0], 0, 0);
        KC2(accA, pan[0], 1, 1);
        if (jp) EPI1(accB);                    // epilogue of jb 2jp-1
        __syncthreads();

        STAGE_HALF(pan[0], b1h, b1l, 0);       // phase A1: jb even, kc2-3
        KC2(accA, pan[1], 0, 2);
        KC2(accA, pan[1], 1, 3);
        __syncthreads();

        ZEROACC(accB);                         // phase B0: jb odd, kc0-1
        STAGE_HALF(pan[1], b1h, b1l, 2);
        KC2(accB, pan[0], 0, 0);
        KC2(accB, pan[0], 1, 1);
        EPI1(accA);                            // epilogue of jb 2jp
        __syncthreads();

        if (jp < 7) STAGE_HALF(pan[0], b2h, b2l, 0);   // phase B1: kc2-3
        KC2(accB, pan[1], 0, 2);
        KC2(accB, pan[1], 1, 3);
        __syncthreads();
    }
    EPI1(accB);                                // jb 15

    // ---- Z reduce -> per-thread iZ row weights ----
#pragma unroll
    for (int rt = 0; rt < 4; ++rt)
#pragma unroll
        for (int rg = 0; rg < 4; ++rg) {
            float s = z[rt][rg];
            s += __shfl_xor(s, 1);
            s += __shfl_xor(s, 2);
            s += __shfl_xor(s, 4);
            s += __shfl_xor(s, 8);
            if (l16 == 0) zl[wr * 64 + rt * 16 + quad * 4 + rg][wc] = s;
        }
    STAGE_HALF(pan[0], sBh, sBl, 0);           // prefetch sweep-2 jb0
    __syncthreads();
    float wrow[4][4];
#pragma unroll
    for (int rt = 0; rt < 4; ++rt)
#pragma unroll
        for (int rg = 0; rg < 4; ++rg) {
            const int row = wr * 64 + rt * 16 + quad * 4 + rg;
            wrow[rt][rg] = 1.0f / (zl[row][0] + zl[row][1] + zl[row][2] + zl[row][3]);
        }

    // ================= sweep 2: weighted col partials =================
#pragma unroll 1
    for (int jp = 0; jp < 8; ++jp) {
        const unsigned short* b0h = sBh + (size_t)(2 * jp) * 128 * DD;
        const unsigned short* b0l = sBl + (size_t)(2 * jp) * 128 * DD;
        const unsigned short* b1h = b0h + 128 * DD;
        const unsigned short* b1l = b0l + 128 * DD;
        const unsigned short* b2h = b1h + 128 * DD;
        const unsigned short* b2l = b1l + 128 * DD;

        ZEROACC(accA);
        STAGE_HALF(pan[1], b0h, b0l, 2);
        KC2(accA, pan[0], 0, 0);
        KC2(accA, pan[0], 1, 1);
        if (jp) EPI2(accB, 2 * jp - 1);
        __syncthreads();

        STAGE_HALF(pan[0], b1h, b1l, 0);
        KC2(accA, pan[1], 0, 2);
        KC2(accA, pan[1], 1, 3);
        __syncthreads();

        ZEROACC(accB);
        STAGE_HALF(pan[1], b1h, b1l, 2);
        KC2(accB, pan[0], 0, 0);
        KC2(accB, pan[0], 1, 1);
        EPI2(accA, 2 * jp);
        __syncthreads();

        if (jp < 7) STAGE_HALF(pan[0], b2h, b2l, 0);
        KC2(accB, pan[1], 0, 2);
        KC2(accB, pan[1], 1, 3);
        __syncthreads();
    }
    EPI2(accB, 15);

    __syncthreads();
#pragma unroll
    for (int g = 0; g < 4; ++g) {
        const int m = tid + g * 512;
        Spart[((size_t)ns * LL + m) * 16 + ib] = scs[m][0] + scs[m][1];
    }
}

// ---------------------------------------------------------------------------
// Kernel 3: exact bottom-k mask via rank counting — R13 broadcast version.
// R12 lesson (LDS model, m134): R8's per-lane double2 j-loop = 8192
// b128-instrs/block ~ 40 us on 64 CUs. New: grid (16 slices, 16 ns) = 256
// blocks (1/CU); 512 thr = 128 rows x 4 j-groups. Within a wave the j-loop
// address is WAVE-UNIFORM (g = tid>>7 constant per wave) -> each double2
// read is a broadcast (1 conflict-free LDS op serves 64 lanes): 256
// instrs/wave instead of 1024 per-lane reads. s built in IDENTICAL fp64
// order; integer count partials summed exactly -> mask bitwise-identical.
// ---------------------------------------------------------------------------
__global__ __launch_bounds__(512) void mask_kernel(
    const float* __restrict__ Spart, unsigned char* __restrict__ maskbuf)
{
    __shared__ double s[LL];               // 16 KB
    __shared__ int cp[4][128];             // 2 KB group partial counts
    const int sl = blockIdx.x;             // row slice 0..15 (128 rows)
    const int ns = blockIdx.y;
    const int tid = threadIdx.x;
    const int r = tid & 127, g = tid >> 7; // row-in-slice, j-group (wave-uniform)

#pragma unroll
    for (int q = 0; q < 4; ++q) {          // build s[2048], same fp64 order
        int m = tid + q * 512;
        const float* sp = Spart + ((size_t)ns * LL + m) * 16;
        double a = 0.0;
#pragma unroll
        for (int t = 0; t < 16; ++t) a += (double)sp[t];
        s[m] = a;
    }
    __syncthreads();

    const double si = s[sl * 128 + r];
    const double2* sv = (const double2*)s;
    const int base = g * 256;              // wave-uniform double2 base
    int cnt = 0;
#pragma unroll 8
    for (int j = 0; j < 256; ++j) {        // broadcast reads: lanes share addr
        double2 p = sv[base + j];
        cnt += (p.x < si) ? 1 : 0;
        cnt += (p.y < si) ? 1 : 0;
    }
    cp[g][r] = cnt;
    __syncthreads();
    if (tid < 128) {
        int c = cp[0][tid] + cp[1][tid] + cp[2][tid] + cp[3][tid];
        maskbuf[ns * LL + sl * 128 + tid] = (c < 1024) ? 1 : 0;
    }
}

// ---------------------------------------------------------------------------
// Kernel 4: blend, all fp32.
// ---------------------------------------------------------------------------
__global__ __launch_bounds__(256) void blend_kernel(
    const float* __restrict__ xt, const float* __restrict__ xf,
    const unsigned char* __restrict__ maskbuf, float* __restrict__ out)
{
    const int idx4 = blockIdx.x * 256 + threadIdx.x;
    const size_t q = (size_t)idx4 * 4;
    const int row = (int)(q >> 7);
    const float4 a = *(const float4*)(xt + q);
    const float4 b = *(const float4*)(xf + q);
    const int mt = maskbuf[row] & 1;
    const int mf = maskbuf[16384 + row] & 1;
    const bool ct = mt && !mf;
    const bool cf = mf && !mt;
    float4 av;
    av.x = 0.5f * (a.x + b.x);  av.y = 0.5f * (a.y + b.y);
    av.z = 0.5f * (a.z + b.z);  av.w = 0.5f * (a.w + b.w);
    float4 o0 = ct ? av : a;
    float4 o1 = cf ? av : b;
    *(float4*)(out + q)                   = o0;
    *(float4*)(out + (size_t)2097152 + q) = o1;
}

// ---------------------------------------------------------------------------
extern "C" void kernel_launch(void* const* d_in, const int* in_sizes, int n_in,
                              void* d_out, int out_size, void* d_ws, size_t ws_size,
                              hipStream_t stream)
{
    const float* xt = (const float*)d_in[0];
    const float* xf = (const float*)d_in[1];
    const float* W  = (const float*)d_in[2];
    const float* b  = (const float*)d_in[3];
    float* out = (float*)d_out;

    // d_out (16.8 MB) holds P split: Ph bf16 [0,8.39MB), Pl bf16 [8.39,16.8MB).
    unsigned short* Ph = (unsigned short*)d_out;
    unsigned short* Pl = Ph + (size_t)NS * SLAB;

    float* Spart = (float*)d_ws;                       // 524288 f
    unsigned char* maskbuf = (unsigned char*)(Spart + (size_t)16 * LL * 16);
    // total ws ~2.2 MB

    proj_kernel<<<dim3(16, NS), 512, 0, stream>>>(xt, xf, W, b, Ph, Pl);
    score_kernel<<<dim3(16, 16), 512, 0, stream>>>(Ph, Pl, Spart);
    mask_kernel<<<dim3(16, NS), 512, 0, stream>>>(Spart, maskbuf);
    blend_kernel<<<2048, 256, 0, stream>>>(xt, xf, maskbuf, out);
}